// Round 1
// baseline (109.091 us; speedup 1.0000x reference)
//
#include <hip/hip_runtime.h>
#include <stdint.h>
#include <stddef.h>

#define IDIM    256
#define FDIM    32
#define ODIM    30

typedef __attribute__((ext_vector_type(8))) short bf16x8;
typedef __attribute__((ext_vector_type(4))) float f32x4;

__device__ __forceinline__ short f2bf(float f) {
    union { float f; unsigned u; } v; v.f = f;
    unsigned r = v.u + 0x7FFFu + ((v.u >> 16) & 1u);
    return (short)(r >> 16);
}

// Kernel 1: M[i][j] = (j>i) ? dot(kernel[i,:],kernel[j,:]) * FW[fi[i]][fi[j]] : 0
// Stored bf16 into ws at byte offset  i*512 + ((2*j) ^ ((i&7)<<4))
// i.e. pre-swizzled so the main kernel can stage it LINEARLY into LDS with
// global_load_lds and read B-fragments with the same XOR swizzle (bank-conflict-free).
__global__ void build_M(const float* __restrict__ K, const float* __restrict__ FW,
                        const int* __restrict__ FI, char* __restrict__ Mws) {
    const int i = blockIdx.x;
    const int j = threadIdx.x;
    float acc = 0.f;
    #pragma unroll
    for (int k = 0; k < ODIM; ++k) acc += K[i*ODIM + k] * K[j*ODIM + k];
    float m = 0.f;
    if (j > i) m = acc * FW[FI[i]*FDIM + FI[j]];
    const unsigned off = (unsigned)i*512u + (((unsigned)(2*j)) ^ ((unsigned)((i & 7) << 4)));
    *(short*)(Mws + off) = f2bf(m);
}

// Main kernel: out[b] = x_b^T M x_b
// 256 blocks x 512 threads. Block handles 256 batch rows; wave w handles rows
// [w*32, w*32+32) as 2 strips of 16. M (bf16, swizzled) resident in 128 KB LDS.
// GEMM: Y[m][n] = sum_k X[m][k] * M[n][k]  (B^T-contiguous reads from LDS),
// then fold out[m] = sum_n X[m][n] * Y[m][n].
__global__ __launch_bounds__(512, 2)
void qform(const float* __restrict__ X, const char* __restrict__ Mws,
           float* __restrict__ out) {
    __shared__ char lds[131072];
    const int tid  = threadIdx.x;
    const int lane = tid & 63;
    const int wave = tid >> 6;
    const int wrow = blockIdx.x * 256 + wave * 32;

    // ---- stage M (128 KB) ws -> LDS, linear copy (ws is pre-swizzled) ----
    #pragma unroll
    for (int it = 0; it < 16; ++it) {
        const char* g = Mws + it*8192 + tid*16;     // per-lane global src
        char*       l = lds + it*8192 + wave*1024;  // wave-uniform dest (+lane*16 by HW)
        __builtin_amdgcn_global_load_lds(
            (const __attribute__((address_space(1))) unsigned int*)g,
            (__attribute__((address_space(3))) unsigned int*)l,
            16, 0, 0);
    }

    // ---- A fragments: X rows f32 -> bf16, 2 strips x 8 k-steps ----
    // A-frag layout (16x16x32): lane l holds A[row = l&15][k = (l>>4)*8 + e]
    bf16x8 afrag[2][8];
    {
        const int arow = lane & 15;
        const int kgrp = (lane >> 4) * 8;
        #pragma unroll
        for (int s = 0; s < 2; ++s) {
            const float* xr = X + (size_t)(wrow + s*16 + arow) * IDIM + kgrp;
            #pragma unroll
            for (int tj = 0; tj < 8; ++tj) {
                float4 f0 = *(const float4*)(xr + tj*32);
                float4 f1 = *(const float4*)(xr + tj*32 + 4);
                bf16x8 a;
                a[0]=f2bf(f0.x); a[1]=f2bf(f0.y); a[2]=f2bf(f0.z); a[3]=f2bf(f0.w);
                a[4]=f2bf(f1.x); a[5]=f2bf(f1.y); a[6]=f2bf(f1.z); a[7]=f2bf(f1.w);
                afrag[s][tj] = a;
            }
        }
    }

    asm volatile("s_waitcnt vmcnt(0)" ::: "memory");
    __syncthreads();

    // ---- MFMA main loop: tj (k-step) outer, all 16 n-tiles' acc live ----
    f32x4 acc[2][16];
    #pragma unroll
    for (int s = 0; s < 2; ++s)
        #pragma unroll
        for (int t = 0; t < 16; ++t)
            acc[s][t] = (f32x4){0.f, 0.f, 0.f, 0.f};

    // B-frag: lane l reads M_lds[row = 16*ti + (l&15)][jbytes = 64*tj + 16*(l>>4)],
    // 16 contiguous bytes, with XOR swizzle ((row&7)<<4) == ((l&7)<<4).
    const unsigned lrow512 = (unsigned)(lane & 15) * 512u;
    const unsigned grp16   = (unsigned)(lane >> 4) * 16u;
    const unsigned xorv    = (unsigned)(lane & 7) << 4;

    #pragma unroll
    for (int tj = 0; tj < 8; ++tj) {
        const unsigned jb = ((unsigned)(tj*64) + grp16) ^ xorv;
        const int timax = 2*tj + 1;   // strictly-lower tiles are all-zero: skip
        #pragma unroll
        for (int ti = 0; ti <= timax && ti < 16; ++ti) {
            bf16x8 b = *(const bf16x8*)(lds + (unsigned)ti*8192u + lrow512 + jb);
            acc[0][ti] = __builtin_amdgcn_mfma_f32_16x16x32_bf16(afrag[0][tj], b, acc[0][ti], 0, 0, 0);
            acc[1][ti] = __builtin_amdgcn_mfma_f32_16x16x32_bf16(afrag[1][tj], b, acc[1][ti], 0, 0, 0);
        }
    }

    // ---- fold with x: out[m] = sum_n X[m][n] * Y[m][n] ----
    // C/D layout: col = l&15 (n within tile), row = (l>>4)*4 + r (m within strip)
    float psum[2][4] = {{0.f,0.f,0.f,0.f},{0.f,0.f,0.f,0.f}};
    const int g4 = (lane >> 4) * 4;
    #pragma unroll
    for (int ti = 0; ti < 16; ++ti) {
        const int col = ti*16 + (lane & 15);
        #pragma unroll
        for (int s = 0; s < 2; ++s) {
            const float* xc = X + (size_t)(wrow + s*16 + g4) * IDIM + col;
            #pragma unroll
            for (int r = 0; r < 4; ++r)
                psum[s][r] += xc[(size_t)r * IDIM] * acc[s][ti][r];
        }
    }

    // ---- reduce over the 16 lanes (n-cols) of each quarter-wave group ----
    #pragma unroll
    for (int s = 0; s < 2; ++s)
        #pragma unroll
        for (int r = 0; r < 4; ++r) {
            float v = psum[s][r];
            v += __shfl_xor(v, 1, 64);
            v += __shfl_xor(v, 2, 64);
            v += __shfl_xor(v, 4, 64);
            v += __shfl_xor(v, 8, 64);
            psum[s][r] = v;
        }

    if ((lane & 15) == 0) {
        #pragma unroll
        for (int s = 0; s < 2; ++s)
            #pragma unroll
            for (int r = 0; r < 4; ++r)
                out[wrow + s*16 + g4 + r] = psum[s][r];
    }
}

extern "C" void kernel_launch(void* const* d_in, const int* in_sizes, int n_in,
                              void* d_out, int out_size, void* d_ws, size_t ws_size,
                              hipStream_t stream) {
    const float* X  = (const float*)d_in[0];   // (65536, 256) f32
    const float* K  = (const float*)d_in[1];   // (256, 30)  f32
    const float* FW = (const float*)d_in[2];   // (32, 32)   f32
    const int*   FI = (const int*)d_in[3];     // (256,)     i32
    char* Mws = (char*)d_ws;                   // needs 128 KB

    build_M<<<dim3(256), dim3(256), 0, stream>>>(K, FW, FI, Mws);

    const int batch = in_sizes[0] / IDIM;      // 65536
    qform<<<dim3(batch / 256), dim3(512), 0, stream>>>(X, Mws, (float*)d_out);
}